// Round 3
// baseline (161.994 us; speedup 1.0000x reference)
//
#include <hip/hip_runtime.h>

// Composite-filter formulation:
//   out[o] = sum_{k=0..54} Cp[r][k] * x[n0 - k],
//     r = (2o+32) % 3, n0 = (2o+32-r)/3,
//     Cp[p][k] = C[p+3k], C[j] = sum_m b[m]*h[j-2m]
//
// R7: direct-global windows: 46us, VALUBusy 22% -> stalled, not VALU-bound.
// R8 FAILED: reg double-buffer, VGPR 128, occupancy halved, 77us.
//   Lesson: latency hiding here comes from TLP (8 waves/SIMD at <=64 VGPR).
// R9: LDS tile + XOR float4-slot swizzle slot(c)=c^((c>>3)&7), 6-reg rotating
//   window. fused < 42.6us. Bench total moved only ~2us -> timed region is
//   dominated by fixed machinery (256MiB poison fill at 43us + 3 launches).
// R10: single-dispatch megakernel. Every block builds the 168-float coeff
//   table in LDS itself (~26-term dot products, hides the x-stage latency);
//   2 extra blocks absorb boundary_fix. No workspace use, 3 dispatches -> 1.
//   Coeff values bit-identical (same summation order; skipped terms are the
//   exact zeros of h's pre-pad), so absmax must stay 0.015625.

#define TPB 256
#define RPT 12                    // outputs per thread
#define OTILE (TPB * RPT)         // 3072 outputs per block
#define NCHUNK 528                // float4 chunks staged per tile (2112 floats)
#define NTAPS 55
#define CPSTRIDE 56               // phase-major coeff stride (float4-aligned)

#define SLOT(c) ((c) ^ (((c) >> 3) & 7))

// Group g covers taps k=4g..4g+3 for 12 outputs d=0..11.
// delta_d = {0,1,2,2,3,4,4,5,6,6,7,8}, phase r_d = (2+2d)%3 -> q2/q1/q0 cycle.
// Window float (54+delta-4g-j) -> chunks: A=w[15-g], B=w[14-g], C=w[13-g], D=w[12-g].
#define GRP12(g, A, B, C, D) {                                          \
    const float4 q2 = c2q[g];                                           \
    const float4 q1 = c1q[g];                                           \
    const float4 q0 = c0q[g];                                           \
    /* j=0 */                                                           \
    a0  += q2.x * C.z;  a1  += q1.x * C.w;  a2  += q0.x * B.x;          \
    a3  += q2.x * B.x;  a4  += q1.x * B.y;  a5  += q0.x * B.z;          \
    a6  += q2.x * B.z;  a7  += q1.x * B.w;  a8  += q0.x * A.x;          \
    a9  += q2.x * A.x;  a10 += q1.x * A.y;  a11 += q0.x * A.z;          \
    /* j=1 */                                                           \
    a0  += q2.y * C.y;  a1  += q1.y * C.z;  a2  += q0.y * C.w;          \
    a3  += q2.y * C.w;  a4  += q1.y * B.x;  a5  += q0.y * B.y;          \
    a6  += q2.y * B.y;  a7  += q1.y * B.z;  a8  += q0.y * B.w;          \
    a9  += q2.y * B.w;  a10 += q1.y * A.x;  a11 += q0.y * A.y;          \
    /* j=2 */                                                           \
    a0  += q2.z * C.x;  a1  += q1.z * C.y;  a2  += q0.z * C.z;          \
    a3  += q2.z * C.z;  a4  += q1.z * C.w;  a5  += q0.z * B.x;          \
    a6  += q2.z * B.x;  a7  += q1.z * B.y;  a8  += q0.z * B.z;          \
    a9  += q2.z * B.z;  a10 += q1.z * B.w;  a11 += q0.z * A.x;          \
    /* j=3 */                                                           \
    a0  += q2.w * D.w;  a1  += q1.w * C.x;  a2  += q0.w * C.y;          \
    a3  += q2.w * C.y;  a4  += q1.w * C.z;  a5  += q0.w * C.w;          \
    a6  += q2.w * C.w;  a7  += q1.w * B.x;  a8  += q0.w * B.y;          \
    a9  += q2.w * B.y;  a10 += q1.w * B.z;  a11 += q0.w * B.w; }

// Tail group: j=0..2 only (k = 52,53,54).
#define GRP12T(g, A, B, C) {                                            \
    const float4 q2 = c2q[g];                                           \
    const float4 q1 = c1q[g];                                           \
    const float4 q0 = c0q[g];                                           \
    a0  += q2.x * C.z;  a1  += q1.x * C.w;  a2  += q0.x * B.x;          \
    a3  += q2.x * B.x;  a4  += q1.x * B.y;  a5  += q0.x * B.z;          \
    a6  += q2.x * B.z;  a7  += q1.x * B.w;  a8  += q0.x * A.x;          \
    a9  += q2.x * A.x;  a10 += q1.x * A.y;  a11 += q0.x * A.z;          \
    a0  += q2.y * C.y;  a1  += q1.y * C.z;  a2  += q0.y * C.w;          \
    a3  += q2.y * C.w;  a4  += q1.y * B.x;  a5  += q0.y * B.y;          \
    a6  += q2.y * B.y;  a7  += q1.y * B.z;  a8  += q0.y * B.w;          \
    a9  += q2.y * B.w;  a10 += q1.y * A.x;  a11 += q0.y * A.y;          \
    a0  += q2.z * C.x;  a1  += q1.z * C.y;  a2  += q0.z * C.z;          \
    a3  += q2.z * C.z;  a4  += q1.z * C.w;  a5  += q0.z * B.x;          \
    a6  += q2.z * B.x;  a7  += q1.z * B.y;  a8  += q0.z * B.z;          \
    a9  += q2.z * B.z;  a10 += q1.z * B.w;  a11 += q0.z * A.x; }

__global__ __launch_bounds__(TPB) void fused_all(
    const float* __restrict__ x, const float* __restrict__ h,
    const float* __restrict__ b, float* __restrict__ out,
    int n_in, int n_out, int out_size, int nmain)
{
    __shared__ float4 xs4[NCHUNK];          // 8448 B, XOR-swizzled float4 slots
    __shared__ float4 cps4[3 * CPSTRIDE / 4]; // 672 B coeff table (16B aligned)
    __shared__ float  h_s[64];
    __shared__ float  b_s[52];

    const int tid = threadIdx.x;
    const int bid = blockIdx.x;

    float* const cps = (float*)cps4;

    // ---------------- boundary blocks (2 at the end of the grid) -----------
    if (bid >= nmain) {
        float* const x_s = (float*)xs4;       // 64 floats
        float* const u_s = ((float*)xs4) + 64; // 50 floats

        if (tid < 63) h_s[tid] = h[tid];
        if (tid < 51) b_s[tid] = b[tid];

        if (bid == nmain) {                   // head: o in [0,50)
            if (tid < 44) x_s[tid] = (tid < n_in) ? x[tid] : 0.0f;
            __syncthreads();
            if (tid < 50) {
                const int s  = 2 * tid + 32;
                const int p0 = s % 3;
                const int q  = s / 3;
                float u = 0.0f;
                #pragma unroll
                for (int i = 0; i <= 20; ++i) {
                    const int xi = q - i;
                    u += h_s[p0 + 3 * i] * ((xi >= 0) ? x_s[xi] : 0.0f);
                }
                u_s[tid] = u;
            }
            __syncthreads();
            if (tid < 50) {
                float acc = 0.0f;
                for (int t = 0; t <= tid; ++t) acc += b_s[tid - t] * u_s[t];
                out[tid] = acc;
            }
        } else {                              // tail: o in [n_out, out_size)
            const int t0   = n_out - 50;
            const int qmin = (2 * t0 + 32) / 3;
            const int xb   = qmin - 20;
            if (tid < 64) {
                const int xi = xb + tid;
                x_s[tid] = (xi >= 0 && xi < n_in) ? x[xi] : 0.0f;
            }
            __syncthreads();
            if (tid < 50) {
                const int t  = t0 + tid;
                const int s  = 2 * t + 32;
                const int p0 = s % 3;
                const int q  = s / 3;
                const int base = q - xb;
                float u = 0.0f;
                #pragma unroll
                for (int i = 0; i <= 20; ++i)
                    u += h_s[p0 + 3 * i] * x_s[base - i];
                u_s[tid] = u;
            }
            __syncthreads();
            const int n_tail = out_size - n_out;   // 96
            if (tid < n_tail) {
                float acc = 0.0f;
                for (int j = tid; j <= 49; ++j) acc += b_s[tid + 50 - j] * u_s[j];
                out[n_out + tid] = acc;
            }
        }
        return;
    }

    // ---------------- main blocks ------------------------------------------
    const int o0      = bid * OTILE;             // multiple of 3072
    const int n_tile0 = 2048 * bid - 44;         // tile x-base, multiple of 4

    if (tid < 63) h_s[tid] = h[tid];
    if (tid < 51) b_s[tid] = b[tid];

    // Issue the x-tile loads early (interior path); their latency hides
    // under the h/b sync + coefficient build below.
    const bool interior = (n_tile0 >= 0) && (n_tile0 + 4 * NCHUNK <= n_in);
    float4 g0, g1, g2;
    if (interior) {
        const float4* gx = (const float4*)(x + n_tile0);
        g0 = gx[tid];
        g1 = gx[tid + 256];
        if (tid < NCHUNK - 512) g2 = gx[tid + 512];
    }
    __syncthreads();                             // h_s, b_s visible

    // Per-block coefficient table: cps[p*56+k] = C[p+3k], C[j]=sum_m b[m]h[j-2m].
    // Tight m-bounds skip only exact-zero terms (h[0..1]=0 pre-pad or out of
    // range); summation order over nonzero terms matches the old build_coeffs,
    // so values are bit-identical.
    if (tid < 3 * CPSTRIDE) {
        const int p = tid / CPSTRIDE;
        const int k = tid - p * CPSTRIDE;
        float acc = 0.0f;
        if (k < NTAPS) {
            const int j  = p + 3 * k;            // 0..164
            const int m0 = max(0, (j - 61) >> 1);   // ceil((j-62)/2)
            const int m1 = min(50, j >> 1);
            for (int m = m0; m <= m1; ++m)
                acc += b_s[m] * h_s[j - 2 * m];
        }
        cps[tid] = acc;
    }

    // Stage x tile into swizzled LDS slots.
    if (interior) {
        xs4[SLOT(tid)]       = g0;
        xs4[SLOT(tid + 256)] = g1;
        if (tid < NCHUNK - 512) xs4[SLOT(tid + 512)] = g2;
    } else {
        float* xsf = (float*)xs4;
        for (int i = tid; i < 4 * NCHUNK; i += TPB) {
            const int n = n_tile0 + i;
            const float v = (n >= 0 && n < n_in) ? x[n] : 0.0f;
            xsf[(SLOT(i >> 2) << 2) | (i & 3)] = v;
        }
    }
    __syncthreads();                             // cps + xs4 ready

    const float4* c2q = cps4 + 2 * (CPSTRIDE / 4);   // phase 2 (o%3==0)
    const float4* c1q = cps4 + 1 * (CPSTRIDE / 4);
    const float4* c0q = cps4;

    float a0 = 0.f, a1 = 0.f, a2 = 0.f, a3  = 0.f, a4  = 0.f, a5  = 0.f;
    float a6 = 0.f, a7 = 0.f, a8 = 0.f, a9  = 0.f, a10 = 0.f, a11 = 0.f;

    // 6-reg rotating window over chunks cbase+15 .. cbase+0 (distance-2 prefetch).
    const int cbase = 2 * tid;
#define XS(j) xs4[SLOT(cbase + (j))]
    {
        float4 r0 = XS(15), r1 = XS(14), r2 = XS(13),
               r3 = XS(12), r4 = XS(11), r5 = XS(10);
        GRP12( 0, r0, r1, r2, r3);  r0 = XS(9);
        GRP12( 1, r1, r2, r3, r4);  r1 = XS(8);
        GRP12( 2, r2, r3, r4, r5);  r2 = XS(7);
        GRP12( 3, r3, r4, r5, r0);  r3 = XS(6);
        GRP12( 4, r4, r5, r0, r1);  r4 = XS(5);
        GRP12( 5, r5, r0, r1, r2);  r5 = XS(4);
        GRP12( 6, r0, r1, r2, r3);  r0 = XS(3);
        GRP12( 7, r1, r2, r3, r4);  r1 = XS(2);
        GRP12( 8, r2, r3, r4, r5);  r2 = XS(1);
        GRP12( 9, r3, r4, r5, r0);  r3 = XS(0);
        GRP12(10, r4, r5, r0, r1);
        GRP12(11, r5, r0, r1, r2);
        GRP12(12, r0, r1, r2, r3);
        GRP12T(13, r1, r2, r3);
    }
#undef XS

    // ---- store 12 outputs ----
    const int ob = o0 + RPT * tid;               // multiple of 12
    if (ob >= 50 && ob + 11 < n_out) {
        float4* o4 = (float4*)(out + ob);        // 16B aligned (ob % 4 == 0)
        o4[0] = make_float4(a0, a1, a2,  a3);
        o4[1] = make_float4(a4, a5, a6,  a7);
        o4[2] = make_float4(a8, a9, a10, a11);
    } else {
        const float accs[RPT] = {a0, a1, a2, a3, a4, a5, a6, a7, a8, a9, a10, a11};
#pragma unroll
        for (int d = 0; d < RPT; ++d) {
            const int o = ob + d;
            if (o >= 50 && o < n_out) out[o] = accs[d];
        }
    }
}

extern "C" void kernel_launch(void* const* d_in, const int* in_sizes, int n_in_arrs,
                              void* d_out, int out_size, void* d_ws, size_t ws_size,
                              hipStream_t stream) {
    const float* x = (const float*)d_in[0];
    const float* h = (const float*)d_in[1];
    const float* b = (const float*)d_in[2];
    float* out = (float*)d_out;

    const int n_in  = in_sizes[0];                    // 8388608
    const int n_out = (int)((long long)n_in * 3 / 2); // 12582912

    const int nmain = (n_out + OTILE - 1) / OTILE;    // 4096
    fused_all<<<nmain + 2, TPB, 0, stream>>>(x, h, b, out,
                                             n_in, n_out, out_size, nmain);
}

// Round 4
// 108.946 us; speedup vs baseline: 1.4869x; 1.4869x over previous
//
#include <hip/hip_runtime.h>

// Composite-filter formulation:
//   out[o] = sum_{k=0..54} Cp[r][k] * x[n0 - k],
//     r = (2o+32) % 3, n0 = (2o+32-r)/3,
//     Cp[p][k] = C[p+3k], C[j] = sum_m b[m]*h[j-2m]
//
// R7: direct-global windows: 46us, VALUBusy 22% -> stalled, not VALU-bound.
// R8 FAILED: reg double-buffer, VGPR 128, occupancy halved, 77us.
//   Lesson: latency hiding here comes from TLP (8 waves/SIMD at <=64 VGPR).
// R9 (best): LDS tile + XOR float4-slot swizzle slot(c)=c^((c>>3)&7), 6-reg
//   rotating window, coeffs via global cp -> s_load -> SGPR operands.
//   fused < 42.6us, total 117us.
// R10 FAILED: megakernel w/ LDS coeff table: per-lane ds_read_b128 of
//   uniform addresses is NOT a free broadcast (5.2M conflict-cycles), and
//   path-merging pushed VGPR to 144 (occupancy 10%). 94us.
//   Lessons: keep coeffs in SGPRs (global + uniform index); keep paths split.
// R11: R9 compute kernel EXACTLY; merge build_coeffs + 2 boundary blocks into
//   one 3-block prep dispatch (boundary doesn't read cp -> legal block-level
//   merge, bit-identical results). 3 dispatches -> 2.

#define TPB 256
#define RPT 12                    // outputs per thread
#define OTILE (TPB * RPT)         // 3072 outputs per block
#define NCHUNK 528                // float4 chunks staged per tile (2112 floats)
#define NTAPS 55
#define CPSTRIDE 56               // phase-major coeff stride (float4-aligned)

#define SLOT(c) ((c) ^ (((c) >> 3) & 7))

// One dispatch, 3 independent blocks:
//   block 0: build cp[3*56] composite coefficients (same order as R9 -> bit-identical)
//   block 1: head boundary (o in [0,50))
//   block 2: tail boundary (o in [n_out, out_size))
__global__ __launch_bounds__(TPB) void prep_k(
    const float* __restrict__ x, const float* __restrict__ h,
    const float* __restrict__ b, float* __restrict__ cp,
    float* __restrict__ out, int n_in, int n_out, int out_size)
{
    __shared__ float h_s[63];
    __shared__ float b_s[51];
    __shared__ float x_s[64];
    __shared__ float u_s[50];

    const int tid = threadIdx.x;
    if (tid < 63) h_s[tid] = h[tid];
    if (tid < 51) b_s[tid] = b[tid];

    if (blockIdx.x == 0) {
        __syncthreads();
        for (int idx = tid; idx < 3 * CPSTRIDE; idx += TPB) {
            const int p = idx / CPSTRIDE;
            const int k = idx - p * CPSTRIDE;
            float acc = 0.0f;
            if (k < NTAPS) {
                const int j = p + 3 * k;
                for (int m = 0; m <= 50; ++m) {
                    const int hi = j - 2 * m;
                    if (hi >= 0 && hi <= 62) acc += b_s[m] * h_s[hi];
                }
            }
            cp[idx] = acc;
        }
    } else if (blockIdx.x == 1) {
        if (tid < 44) x_s[tid] = (tid < n_in) ? x[tid] : 0.0f;
        __syncthreads();
        if (tid < 50) {
            const int s  = 2 * tid + 32;
            const int p0 = s % 3;
            const int q  = s / 3;
            float u = 0.0f;
            #pragma unroll
            for (int i = 0; i <= 20; ++i) {
                const int xi = q - i;
                u += h_s[p0 + 3 * i] * ((xi >= 0) ? x_s[xi] : 0.0f);
            }
            u_s[tid] = u;
        }
        __syncthreads();
        if (tid < 50) {
            float acc = 0.0f;
            for (int t = 0; t <= tid; ++t) acc += b_s[tid - t] * u_s[t];
            out[tid] = acc;
        }
    } else {
        const int t0   = n_out - 50;
        const int qmin = (2 * t0 + 32) / 3;
        const int xb   = qmin - 20;
        if (tid < 64) {
            const int xi = xb + tid;
            x_s[tid] = (xi >= 0 && xi < n_in) ? x[xi] : 0.0f;
        }
        __syncthreads();
        if (tid < 50) {
            const int t  = t0 + tid;
            const int s  = 2 * t + 32;
            const int p0 = s % 3;
            const int q  = s / 3;
            const int base = q - xb;
            float u = 0.0f;
            #pragma unroll
            for (int i = 0; i <= 20; ++i)
                u += h_s[p0 + 3 * i] * x_s[base - i];
            u_s[tid] = u;
        }
        __syncthreads();
        const int n_tail = out_size - n_out;   // 96
        if (tid < n_tail) {
            float acc = 0.0f;
            for (int j = tid; j <= 49; ++j) acc += b_s[tid + 50 - j] * u_s[j];
            out[n_out + tid] = acc;
        }
    }
}

// Group g covers taps k=4g..4g+3 for 12 outputs d=0..11.
// delta_d = {0,1,2,2,3,4,4,5,6,6,7,8}, phase r_d = (2+2d)%3 -> q2/q1/q0 cycle.
// Window float (54+delta-4g-j) -> chunks: A=w[15-g], B=w[14-g], C=w[13-g], D=w[12-g].
#define GRP12(g, A, B, C, D) {                                          \
    const float4 q2 = c2q[g];                                           \
    const float4 q1 = c1q[g];                                           \
    const float4 q0 = c0q[g];                                           \
    /* j=0 */                                                           \
    a0  += q2.x * C.z;  a1  += q1.x * C.w;  a2  += q0.x * B.x;          \
    a3  += q2.x * B.x;  a4  += q1.x * B.y;  a5  += q0.x * B.z;          \
    a6  += q2.x * B.z;  a7  += q1.x * B.w;  a8  += q0.x * A.x;          \
    a9  += q2.x * A.x;  a10 += q1.x * A.y;  a11 += q0.x * A.z;          \
    /* j=1 */                                                           \
    a0  += q2.y * C.y;  a1  += q1.y * C.z;  a2  += q0.y * C.w;          \
    a3  += q2.y * C.w;  a4  += q1.y * B.x;  a5  += q0.y * B.y;          \
    a6  += q2.y * B.y;  a7  += q1.y * B.z;  a8  += q0.y * B.w;          \
    a9  += q2.y * B.w;  a10 += q1.y * A.x;  a11 += q0.y * A.y;          \
    /* j=2 */                                                           \
    a0  += q2.z * C.x;  a1  += q1.z * C.y;  a2  += q0.z * C.z;          \
    a3  += q2.z * C.z;  a4  += q1.z * C.w;  a5  += q0.z * B.x;          \
    a6  += q2.z * B.x;  a7  += q1.z * B.y;  a8  += q0.z * B.z;          \
    a9  += q2.z * B.z;  a10 += q1.z * B.w;  a11 += q0.z * A.x;          \
    /* j=3 */                                                           \
    a0  += q2.w * D.w;  a1  += q1.w * C.x;  a2  += q0.w * C.y;          \
    a3  += q2.w * C.y;  a4  += q1.w * C.z;  a5  += q0.w * C.w;          \
    a6  += q2.w * C.w;  a7  += q1.w * B.x;  a8  += q0.w * B.y;          \
    a9  += q2.w * B.y;  a10 += q1.w * B.z;  a11 += q0.w * B.w; }

// Tail group: j=0..2 only (k = 52,53,54).
#define GRP12T(g, A, B, C) {                                            \
    const float4 q2 = c2q[g];                                           \
    const float4 q1 = c1q[g];                                           \
    const float4 q0 = c0q[g];                                           \
    a0  += q2.x * C.z;  a1  += q1.x * C.w;  a2  += q0.x * B.x;          \
    a3  += q2.x * B.x;  a4  += q1.x * B.y;  a5  += q0.x * B.z;          \
    a6  += q2.x * B.z;  a7  += q1.x * B.w;  a8  += q0.x * A.x;          \
    a9  += q2.x * A.x;  a10 += q1.x * A.y;  a11 += q0.x * A.z;          \
    a0  += q2.y * C.y;  a1  += q1.y * C.z;  a2  += q0.y * C.w;          \
    a3  += q2.y * C.w;  a4  += q1.y * B.x;  a5  += q0.y * B.y;          \
    a6  += q2.y * B.y;  a7  += q1.y * B.z;  a8  += q0.y * B.w;          \
    a9  += q2.y * B.w;  a10 += q1.y * A.x;  a11 += q0.y * A.y;          \
    a0  += q2.z * C.x;  a1  += q1.z * C.y;  a2  += q0.z * C.z;          \
    a3  += q2.z * C.z;  a4  += q1.z * C.w;  a5  += q0.z * B.x;          \
    a6  += q2.z * B.x;  a7  += q1.z * B.y;  a8  += q0.z * B.z;          \
    a9  += q2.z * B.z;  a10 += q1.z * B.w;  a11 += q0.z * A.x; }

__global__ __launch_bounds__(TPB) void fused_fast(
    const float* __restrict__ x, const float* __restrict__ cp,
    float* __restrict__ out, int n_in, int n_out)
{
    __shared__ float4 xs4[NCHUNK];   // 8448 B, XOR-swizzled float4 slots

    const int tid = threadIdx.x;
    const int bt  = blockIdx.x;
    const int o0  = bt * OTILE;                  // multiple of 3072
    const int n_tile0 = 2048 * bt - 44;          // tile x-base, multiple of 4

    const float4* c2q = (const float4*)(cp + 2 * CPSTRIDE);  // phase 2 (o%3==0)
    const float4* c1q = (const float4*)(cp + 1 * CPSTRIDE);
    const float4* c0q = (const float4*)(cp + 0 * CPSTRIDE);

    // ---- stage tile into LDS (swizzled slots) ----
    // interior: staging reads [n_tile0, n_tile0 + 2112) fully inside x
    const bool interior = (n_tile0 >= 0) && (n_tile0 + 4 * NCHUNK <= n_in);
    if (interior) {
        const float4* gx = (const float4*)(x + n_tile0);
        const float4 g0 = gx[tid];
        const float4 g1 = gx[tid + 256];
        xs4[SLOT(tid)]       = g0;
        xs4[SLOT(tid + 256)] = g1;
        if (tid < NCHUNK - 512) {
            xs4[SLOT(tid + 512)] = gx[tid + 512];
        }
    } else {
        float* xsf = (float*)xs4;
        for (int i = tid; i < 4 * NCHUNK; i += TPB) {
            const int n = n_tile0 + i;
            const float v = (n >= 0 && n < n_in) ? x[n] : 0.0f;
            xsf[(SLOT(i >> 2) << 2) | (i & 3)] = v;
        }
    }
    __syncthreads();

    float a0 = 0.f, a1 = 0.f, a2 = 0.f, a3  = 0.f, a4  = 0.f, a5  = 0.f;
    float a6 = 0.f, a7 = 0.f, a8 = 0.f, a9  = 0.f, a10 = 0.f, a11 = 0.f;

    // ---- compute: 6-reg rotating window over chunks cbase+15 .. cbase+0 ----
    // XS(j) = tile chunk (2*tid + j), swizzled.
    const int cbase = 2 * tid;
#define XS(j) xs4[SLOT(cbase + (j))]
    {
        float4 r0 = XS(15), r1 = XS(14), r2 = XS(13),
               r3 = XS(12), r4 = XS(11), r5 = XS(10);
        GRP12( 0, r0, r1, r2, r3);  r0 = XS(9);
        GRP12( 1, r1, r2, r3, r4);  r1 = XS(8);
        GRP12( 2, r2, r3, r4, r5);  r2 = XS(7);
        GRP12( 3, r3, r4, r5, r0);  r3 = XS(6);
        GRP12( 4, r4, r5, r0, r1);  r4 = XS(5);
        GRP12( 5, r5, r0, r1, r2);  r5 = XS(4);
        GRP12( 6, r0, r1, r2, r3);  r0 = XS(3);
        GRP12( 7, r1, r2, r3, r4);  r1 = XS(2);
        GRP12( 8, r2, r3, r4, r5);  r2 = XS(1);
        GRP12( 9, r3, r4, r5, r0);  r3 = XS(0);
        GRP12(10, r4, r5, r0, r1);
        GRP12(11, r5, r0, r1, r2);
        GRP12(12, r0, r1, r2, r3);
        GRP12T(13, r1, r2, r3);
    }
#undef XS

    // ---- store 12 outputs ----
    const int ob = o0 + RPT * tid;               // multiple of 12
    if (ob >= 50 && ob + 11 < n_out) {
        float4* o4 = (float4*)(out + ob);        // 16B aligned (ob % 4 == 0)
        o4[0] = make_float4(a0, a1, a2,  a3);
        o4[1] = make_float4(a4, a5, a6,  a7);
        o4[2] = make_float4(a8, a9, a10, a11);
    } else {
        const float accs[RPT] = {a0, a1, a2, a3, a4, a5, a6, a7, a8, a9, a10, a11};
#pragma unroll
        for (int d = 0; d < RPT; ++d) {
            const int o = ob + d;
            if (o >= 50 && o < n_out) out[o] = accs[d];
        }
    }
}

extern "C" void kernel_launch(void* const* d_in, const int* in_sizes, int n_in_arrs,
                              void* d_out, int out_size, void* d_ws, size_t ws_size,
                              hipStream_t stream) {
    const float* x = (const float*)d_in[0];
    const float* h = (const float*)d_in[1];
    const float* b = (const float*)d_in[2];
    float* out = (float*)d_out;
    float* cp  = (float*)d_ws;                        // 3*56*4 = 672 bytes

    const int n_in  = in_sizes[0];                    // 8388608
    const int n_out = (int)((long long)n_in * 3 / 2); // 12582912

    prep_k<<<3, TPB, 0, stream>>>(x, h, b, cp, out, n_in, n_out, out_size);

    const int nblocks = (n_out + OTILE - 1) / OTILE;  // 4096
    fused_fast<<<nblocks, TPB, 0, stream>>>(x, cp, out, n_in, n_out);
}